// Round 6
// baseline (697.976 us; speedup 1.0000x reference)
//
#include <hip/hip_runtime.h>
#include <hip/hip_bf16.h>

typedef float BF;
__device__ __forceinline__ float ldf(const BF* p, int i) { return p[i]; }

typedef _Float16 h8 __attribute__((ext_vector_type(8)));
typedef float f4 __attribute__((ext_vector_type(4)));

static constexpr int N_NODES = 20000;
static constexpr int N_EDGES = 50000;
static constexpr int E_PAD   = 50176;  // 392*128
static constexpr int N_TILES = 392;    // 128-edge tiles
static constexpr int N_PAD   = 20032;  // 313*64
static constexpr int BROW    = 136;    // k_gru LDS row
static constexpr int MAXSEG  = 2048;

__device__ __forceinline__ float sigf(float x) { return 1.f / (1.f + __expf(-x)); }
__device__ __forceinline__ float tanh_f(float x) {
  float e = __expf(2.f * x);
  return 1.f - 2.f / (e + 1.f);
}

// ================= mega-prep =================
static constexpr int S_LIN0 = 5000;
static constexpr int S_MLP1 = E_PAD * 128 / 256;  // 25088
static constexpr int S_W2   = 2048;
static constexpr int S_WCAT = 128;
static constexpr int S_B2TP = 16;                 // 8 combos * 512 halves
static constexpr int S_DEG  = 196;
static constexpr int S_SPAD = 196;
static constexpr int PREP_BLOCKS = S_LIN0 + S_MLP1 + S_W2 + S_WCAT + S_B2TP + 1 + 1 + S_DEG + S_SPAD;

__global__ void k_prep(const BF* __restrict__ x, const BF* __restrict__ ea,
                       const int* __restrict__ batch, const int* __restrict__ src,
                       const int* __restrict__ dst,
                       const BF* __restrict__ w0, const BF* __restrict__ b0,
                       const BF* __restrict__ w1, const BF* __restrict__ b1,
                       const BF* __restrict__ w2, const BF* __restrict__ b2,
                       const BF* __restrict__ gwih, const BF* __restrict__ gwhh,
                       const BF* __restrict__ gbih, const BF* __restrict__ gbhh,
                       float* __restrict__ h, _Float16* __restrict__ h16,
                       _Float16* __restrict__ hidf, _Float16* __restrict__ Q,
                       _Float16* __restrict__ Wcat, float* __restrict__ bcat,
                       _Float16* __restrict__ b2tp, int* __restrict__ seg,
                       int* __restrict__ degi, int* __restrict__ spad) {
  int bid = blockIdx.x, t = threadIdx.x;
  if (bid < S_LIN0) {                       // lin0 -> h (f32) + h16 (f16)
    int idx = bid * 256 + t, n = idx >> 6, o = idx & 63;
    float acc = ldf(b0, o);
#pragma unroll
    for (int f = 0; f < 16; ++f) acc += ldf(x, n * 16 + f) * ldf(w0, o * 16 + f);
    float v = fmaxf(acc, 0.f);
    h[idx] = v;
    h16[idx] = (_Float16)v;
    return;
  }
  bid -= S_LIN0;
  if (bid < S_MLP1) {                       // edge MLP layer1 -> f16 (pad rows zero)
    int idx = bid * 256 + t, e = idx >> 7, j = idx & 127;
    float v = 0.f;
    if (e < N_EDGES) {
      float acc = ldf(b1, j);
#pragma unroll
      for (int i = 0; i < 5; ++i) acc += ldf(ea, e * 5 + i) * ldf(w1, j * 5 + i);
      v = fmaxf(acc, 0.f);
    }
    hidf[idx] = (_Float16)v;
    return;
  }
  bid -= S_MLP1;
  if (bid < S_W2) {                         // w2 -> f16
    int i = bid * 256 + t;
    Q[i] = (_Float16)ldf(w2, i);
    return;
  }
  bid -= S_W2;
  if (bid < S_WCAT) {                       // GRU weight pack
    int idx = bid * 256 + t, row = idx >> 7, k = idx & 127;
    int g = row >> 6, rr = row & 63;
    float v = 0.f;
    if (g == 0) v = (k < 64) ? ldf(gwih, rr * 64 + k) : ldf(gwhh, rr * 64 + (k - 64));
    else if (g == 1) v = (k < 64) ? ldf(gwih, (64 + rr) * 64 + k) : ldf(gwhh, (64 + rr) * 64 + (k - 64));
    else if (g == 2) v = (k < 64) ? ldf(gwih, (128 + rr) * 64 + k) : 0.f;
    else v = (k < 64) ? 0.f : ldf(gwhh, (128 + rr) * 64 + (k - 64));
    Wcat[idx] = (_Float16)v;
    return;
  }
  bid -= S_WCAT;
  if (bid < S_B2TP) {                       // per-combo b2 slice [combo][n16][kk32]
    int idx = bid * 256 + t;
    int combo = idx >> 9, rem = idx & 511, n = rem >> 5, kk = rem & 31;
    int oq = combo & 3, dh = combo >> 2;
    b2tp[idx] = (_Float16)ldf(b2, (dh * 32 + kk) * 64 + oq * 16 + n);
    return;
  }
  bid -= S_B2TP;
  if (bid == 0) {                           // bcat
    float v;
    if (t < 128) v = ldf(gbih, t) + ldf(gbhh, t);
    else if (t < 192) v = ldf(gbih, t);
    else v = ldf(gbhh, t - 64);
    bcat[t] = v;
    return;
  }
  bid -= 1;
  if (bid == 0) {                           // seg starts (batch sorted)
    if (t > 128) return;
    if (t == 128) { seg[128] = N_NODES; return; }
    int lo = 0, hi = N_NODES;
    while (lo < hi) {
      int mid = (lo + hi) >> 1;
      if (batch[mid] < t) lo = mid + 1; else hi = mid;
    }
    seg[t] = lo;
    return;
  }
  bid -= 1;
  if (bid < S_DEG) {                        // in-degree counts (int)
    int e = bid * 256 + t;
    if (e < N_EDGES) atomicAdd(&degi[dst[e]], 1);
    return;
  }
  bid -= S_DEG;
  {                                         // padded src
    int e = bid * 256 + t;
    if (e < E_PAD) spad[e] = (e < N_EDGES) ? src[e] : 0;
  }
}

// ================= CSR build =================
__global__ void k_scan(const int* __restrict__ degi, int* __restrict__ off,
                       int* __restrict__ cursor) {
  __shared__ int sd[256];
  int t = threadIdx.x;
  int running = 0;
  for (int base = 0; base < N_NODES; base += 256) {
    int v = base + t;
    int x = (v < N_NODES) ? degi[v] : 0;
    sd[t] = x;
    __syncthreads();
#pragma unroll
    for (int o = 1; o < 256; o <<= 1) {
      int val = (t >= o) ? sd[t - o] : 0;
      __syncthreads();
      sd[t] += val;
      __syncthreads();
    }
    if (v < N_NODES) {
      int excl = running + sd[t] - x;
      off[v] = excl;
      cursor[v] = excl;
    }
    running += sd[255];
    __syncthreads();
  }
  if (t == 0) off[N_NODES] = running;
}

__global__ void k_fill(const int* __restrict__ dst, int* __restrict__ cursor,
                       int* __restrict__ csr) {
  int e = blockIdx.x * 256 + threadIdx.x;
  if (e < N_EDGES) {
    int pos = atomicAdd(&cursor[dst[e]], 1);
    csr[pos] = e;
  }
}

// ================= NNConv message kernel v6 =================
// grid 256 blocks = 8 combos (oq 4 x dh 2) x 32; block 512 thr = 8 waves.
// B combo-slice (K=4096 flat = 32d x 128k, o=16) fully LDS-resident (128 KB,
// [ks*16+n][32] layout: bank-uniform for b128 frag reads). ONE barrier total;
// each wave loops independently over 128-edge tiles. Per-edge partials are
// plain-stored to pbuf[e][dh][64] (no atomics -> no cross-XCD ping-pong).
__launch_bounds__(512, 2)
__global__ void k_msg(const _Float16* __restrict__ h16, const _Float16* __restrict__ hidf,
                      const _Float16* __restrict__ Q, const _Float16* __restrict__ b2tp,
                      const int* __restrict__ spad, float* __restrict__ pbuf) {
  __shared__ _Float16 b_lds[2048 * 32];   // 128 KB
  __shared__ _Float16 b2l[16 * 32];       // 1 KB
  const int tid = threadIdx.x;
  const int combo = blockIdx.x >> 5, blkin = blockIdx.x & 31;
  const int oq = combo & 3, dh = combo >> 2;
  const int wv = tid >> 6, ln = tid & 63;
  const int m0 = ln & 15, quad = ln >> 4;

  // ---- stage B slice: 8192 uint4 chunks, 16/thread ----
#pragma unroll
  for (int i = 0; i < 16; ++i) {
    int c = tid + i * 512;
    int dl = c >> 8, n = (c >> 4) & 15, kc = c & 15;
    int row = (dh * 32 + dl) * 64 + oq * 16 + n;
    uint4 v = *(const uint4*)(Q + (size_t)row * 128 + kc * 8);
    int ks = dl * 4 + (kc >> 2), kk = (kc & 3) * 8;
    *(uint4*)&b_lds[(ks * 16 + n) * 32 + kk] = v;
  }
  if (tid < 64) {
    int n = tid >> 2, kc = tid & 3;
    *(uint4*)&b2l[n * 32 + kc * 8] = *(const uint4*)(b2tp + combo * 512 + n * 32 + kc * 8);
  }
  __syncthreads();

  for (int wt = blkin * 8 + wv; wt < N_TILES; wt += 256) {
    int tb = wt * 128;
    int sp[8];
    h8 hvv[8][4];
#pragma unroll
    for (int mt = 0; mt < 8; ++mt) {
      int e = tb + mt * 16 + m0;
      sp[mt] = spad[e];
      const _Float16* hp = hidf + (size_t)e * 128 + quad * 8;
#pragma unroll
      for (int c = 0; c < 4; ++c) hvv[mt][c] = *(const h8*)(hp + c * 32);
    }
    f4 acc[8];
#pragma unroll
    for (int mt = 0; mt < 8; ++mt)
#pragma unroll
      for (int j = 0; j < 4; ++j) acc[mt][j] = 0.f;

    for (int g = 0; g < 4; ++g) {
      h8 sv[8];
#pragma unroll
      for (int mt = 0; mt < 8; ++mt)
        sv[mt] = *(const h8*)(h16 + (size_t)sp[mt] * 64 + dh * 32 + g * 8);
      const _Float16* bg = &b_lds[(size_t)g * 32 * 512];  // ks0 = g*32
#pragma unroll
      for (int dl = 0; dl < 8; ++dl) {
#pragma unroll
        for (int c = 0; c < 4; ++c) {
          h8 b = *(const h8*)(bg + ((dl * 4 + c) * 16 + m0) * 32 + quad * 8);
#pragma unroll
          for (int mt = 0; mt < 8; ++mt) {
            h8 a = hvv[mt][c] * sv[mt][dl];
            acc[mt] = __builtin_amdgcn_mfma_f32_16x16x32_f16(a, b, acc[mt], 0, 0, 0);
          }
        }
      }
    }
    // b2 term: one extra K-step, A = s(d-half), B = b2^T slice
    {
      h8 b = *(const h8*)&b2l[m0 * 32 + quad * 8];
#pragma unroll
      for (int mt = 0; mt < 8; ++mt) {
        h8 a = *(const h8*)(h16 + (size_t)sp[mt] * 64 + dh * 32 + quad * 8);
        acc[mt] = __builtin_amdgcn_mfma_f32_16x16x32_f16(a, b, acc[mt], 0, 0, 0);
      }
    }
    // plain stores: pbuf[e][dh][oq*16 + m0]
#pragma unroll
    for (int mt = 0; mt < 8; ++mt)
#pragma unroll
      for (int r = 0; r < 4; ++r) {
        int e = tb + mt * 16 + quad * 4 + r;
        pbuf[(size_t)e * 128 + dh * 64 + oq * 16 + m0] = acc[mt][r];
      }
  }
}

// ================= fused CSR gather + m-build + GRU =================
__launch_bounds__(256)
__global__ void k_gru(const float* __restrict__ pbuf, const int* __restrict__ off,
                      const int* __restrict__ csr, const BF* __restrict__ convb,
                      const _Float16* __restrict__ W, const float* __restrict__ bcat,
                      float* __restrict__ h, _Float16* __restrict__ h16) {
  __shared__ _Float16 xa[64 * BROW];
  __shared__ _Float16 wb[256 * BROW];
  __shared__ float bsh[256];
  int tid = threadIdx.x;
  int wv = tid >> 6, ln = tid & 63, m0 = ln & 15, quad = ln >> 4;
  int rowblk = blockIdx.x * 64;
  bsh[tid] = bcat[tid];
  // phase A: per-node CSR gather-reduce -> m, pack X rows in LDS (lane = o)
  {
    float cb = ldf(convb, ln);
#pragma unroll
    for (int j = 0; j < 16; ++j) {
      int r = wv * 16 + j;
      int v = rowblk + r;
      _Float16 mv = (_Float16)0.f, hvv = (_Float16)0.f;
      if (v < N_NODES) {
        int eb = off[v], ee = off[v + 1];
        float acc = 0.f;
        for (int i = eb; i < ee; ++i) {
          int eid = csr[i];
          const float* pr = pbuf + (size_t)eid * 128;
          acc += pr[ln] + pr[64 + ln];
        }
        float inv = 1.f / (float)max(ee - eb, 1);
        mv = (_Float16)fmaxf(acc * inv + cb, 0.f);
        hvv = (_Float16)h[(size_t)v * 64 + ln];
      }
      xa[r * BROW + ln] = mv;
      xa[r * BROW + 64 + ln] = hvv;
    }
  }
#pragma unroll
  for (int c = 0; c < 16; ++c) {
    int i = tid + c * 256, r = i >> 4, ch = i & 15;
    *(uint4*)&wb[r * BROW + ch * 8] = *(const uint4*)(W + (size_t)r * 128 + ch * 8);
  }
  __syncthreads();
  f4 acc[16];
#pragma unroll
  for (int ct = 0; ct < 16; ++ct)
#pragma unroll
    for (int j = 0; j < 4; ++j) acc[ct][j] = 0.f;
#pragma unroll
  for (int t = 0; t < 4; ++t) {
    h8 a = *(const h8*)&xa[(wv * 16 + m0) * BROW + t * 32 + quad * 8];
#pragma unroll
    for (int ct = 0; ct < 16; ++ct) {
      h8 b = *(const h8*)&wb[(ct * 16 + m0) * BROW + t * 32 + quad * 8];
      acc[ct] = __builtin_amdgcn_mfma_f32_16x16x32_f16(a, b, acc[ct], 0, 0, 0);
    }
  }
#pragma unroll
  for (int c0 = 0; c0 < 4; ++c0) {
    int o = c0 * 16 + m0;
    float br = bsh[o], bz = bsh[64 + o], bn = bsh[128 + o], bh2 = bsh[192 + o];
#pragma unroll
    for (int r = 0; r < 4; ++r) {
      int row = rowblk + wv * 16 + quad * 4 + r;
      if (row < N_NODES) {
        float rr = sigf(acc[c0][r] + br);
        float zz = sigf(acc[c0 + 4][r] + bz);
        float nn = tanh_f(acc[c0 + 8][r] + bn + rr * (acc[c0 + 12][r] + bh2));
        size_t hi = (size_t)row * 64 + o;
        float hp = h[hi];
        float hn = (1.f - zz) * nn + zz * hp;
        h[hi] = hn;
        h16[hi] = (_Float16)hn;
      }
    }
  }
}

// ================= fully fused Set2Set =================
__launch_bounds__(256)
__global__ void k_s2s(const float* __restrict__ h, const int* __restrict__ seg,
                      const BF* __restrict__ wih, const BF* __restrict__ whh,
                      const BF* __restrict__ bih, const BF* __restrict__ bhh,
                      float* __restrict__ outp) {
  __shared__ float xrow[128], g[256], qrow[64], hc[64], ccs[64], rr_[64];
  __shared__ float evals[MAXSEG];
  __shared__ float wred[4], rpart[256];
  int b = blockIdx.x, t = threadIdx.x;
  int wv = t >> 6, ln = t & 63;
  if (t < 64) { hc[t] = 0.f; ccs[t] = 0.f; rr_[t] = 0.f; }
  __syncthreads();
  int start = seg[b], end = seg[b + 1];
  int cnt = end - start;
  for (int st = 0; st < 3; ++st) {
    if (t < 64) xrow[t] = hc[t];
    else if (t < 128) xrow[t] = rr_[t - 64];
    __syncthreads();
    {
      float acc = ldf(bih, t) + ldf(bhh, t);
      const BF* wr = wih + t * 128;
      for (int i = 0; i < 128; ++i) acc += xrow[i] * ldf(wr, i);
      const BF* wr2 = whh + t * 64;
      for (int i = 0; i < 64; ++i) acc += xrow[i] * ldf(wr2, i);
      g[t] = acc;
    }
    __syncthreads();
    if (t < 64) {
      float ig = sigf(g[t]), fg = sigf(g[64 + t]);
      float gg = tanh_f(g[128 + t]), og = sigf(g[192 + t]);
      float c = fg * ccs[t] + ig * gg;
      ccs[t] = c;
      float hn = og * tanh_f(c);
      hc[t] = hn;
      qrow[t] = hn;
    }
    __syncthreads();
    float mw = -3.4e38f;
    for (int n = start + wv; n < end; n += 4) {
      float p = h[(size_t)n * 64 + ln] * qrow[ln];
#pragma unroll
      for (int off = 32; off > 0; off >>= 1) p += __shfl_xor(p, off);
      if (ln == 0) evals[n - start] = p;
      mw = fmaxf(mw, p);
    }
    if (ln == 0) wred[wv] = mw;
    __syncthreads();
    float gmax = fmaxf(fmaxf(wred[0], wred[1]), fmaxf(wred[2], wred[3]));
    __syncthreads();
    float psum = 0.f;
    for (int i = t; i < cnt; i += 256) {
      float a = __expf(evals[i] - gmax);
      evals[i] = a;
      psum += a;
    }
#pragma unroll
    for (int off = 32; off > 0; off >>= 1) psum += __shfl_xor(psum, off);
    if (ln == 0) wred[wv] = psum;
    __syncthreads();
    float inv = 1.f / fmaxf(wred[0] + wred[1] + wred[2] + wred[3], 1e-30f);
    float racc = 0.f;
    for (int n = start + wv; n < end; n += 4)
      racc += evals[n - start] * h[(size_t)n * 64 + ln];
    rpart[wv * 64 + ln] = racc;
    __syncthreads();
    if (t < 64)
      rr_[t] = (rpart[t] + rpart[64 + t] + rpart[128 + t] + rpart[192 + t]) * inv;
    __syncthreads();
  }
  if (t < 128) outp[b * 128 + t] = (t < 64) ? hc[t] : rr_[t - 64];
}

// ================= launch =================
extern "C" void kernel_launch(void* const* d_in, const int* in_sizes, int n_in,
                              void* d_out, int out_size, void* d_ws, size_t ws_size,
                              hipStream_t stream) {
  const BF* x      = (const BF*)d_in[0];
  const int* ei    = (const int*)d_in[1];
  const BF* ea     = (const BF*)d_in[2];
  const int* batch = (const int*)d_in[3];
  const BF* w0     = (const BF*)d_in[4];
  const BF* b0     = (const BF*)d_in[5];
  const BF* w1     = (const BF*)d_in[6];
  const BF* b1     = (const BF*)d_in[7];
  const BF* w2     = (const BF*)d_in[8];
  const BF* b2     = (const BF*)d_in[9];
  const BF* convb  = (const BF*)d_in[10];
  const BF* gwih   = (const BF*)d_in[11];
  const BF* gwhh   = (const BF*)d_in[12];
  const BF* gbih   = (const BF*)d_in[13];
  const BF* gbhh   = (const BF*)d_in[14];
  const BF* lwih   = (const BF*)d_in[15];
  const BF* lwhh   = (const BF*)d_in[16];
  const BF* lbih   = (const BF*)d_in[17];
  const BF* lbhh   = (const BF*)d_in[18];
  const int* src = ei;
  const int* dstp = ei + N_EDGES;

  char* w = (char*)d_ws;
  size_t off_b = 0;
  auto take = [&](size_t bytes) -> void* {
    void* p = w + off_b;
    off_b = (off_b + bytes + 255) & ~(size_t)255;
    return p;
  };
  _Float16* Qf16 = (_Float16*)take((size_t)4096 * 128 * 2);
  _Float16* hidf = (_Float16*)take((size_t)E_PAD * 128 * 2);
  float* h       = (float*)take((size_t)N_NODES * 64 * 4);
  _Float16* h16  = (_Float16*)take((size_t)N_NODES * 64 * 2);
  float* pbuf    = (float*)take((size_t)E_PAD * 128 * 4);
  _Float16* Wcat = (_Float16*)take((size_t)256 * 128 * 2);
  float* bcat    = (float*)take((size_t)256 * 4);
  _Float16* b2tp = (_Float16*)take((size_t)8 * 512 * 2);
  int*   seg     = (int*)take((size_t)129 * 4);
  int*   degi    = (int*)take((size_t)N_NODES * 4);
  int*   off     = (int*)take((size_t)(N_NODES + 1) * 4);
  int*   cursor  = (int*)take((size_t)N_NODES * 4);
  int*   csr     = (int*)take((size_t)N_EDGES * 4);
  int*   spad    = (int*)take((size_t)E_PAD * 4);

  hipMemsetAsync(degi, 0, (size_t)N_NODES * 4, stream);
  k_prep<<<PREP_BLOCKS, 256, 0, stream>>>(x, ea, batch, src, dstp, w0, b0, w1, b1,
                                          w2, b2, gwih, gwhh, gbih, gbhh,
                                          h, h16, hidf, Qf16, Wcat, bcat, b2tp,
                                          seg, degi, spad);
  k_scan<<<1, 256, 0, stream>>>(degi, off, cursor);
  k_fill<<<196, 256, 0, stream>>>(dstp, cursor, csr);
  for (int it = 0; it < 3; ++it) {
    k_msg<<<256, 512, 0, stream>>>(h16, hidf, Qf16, b2tp, spad, pbuf);
    k_gru<<<N_PAD / 64, 256, 0, stream>>>(pbuf, off, csr, convb, Wcat, bcat, h, h16);
  }
  k_s2s<<<128, 256, 0, stream>>>(h, seg, lwih, lwhh, lbih, lbhh, (float*)d_out);
}